// Round 1
// baseline (85.048 us; speedup 1.0000x reference)
//
#include <hip/hip_runtime.h>
#include <math.h>

// Problem: B=32, La=Lb=2048. embed_dim=1 MHA degenerates to:
//   q=a*wq+bq; k=b*wk+bk; v=b*wv+bv  (all scalar affine)
//   ctx[b,i] = sum_j softmax_j(q_i*k_j) * v_j
//   out = gelu_exact(ctx*ow + ob + a)
// Compute-bound: 134M (i,j) pairs, ~3 VALU + 1 exp each -> VALU floor ~12us.
// Design: k,v staged in LDS once per block; MI=4 i per thread amortizes each
// LDS read over 4 exp chains (else LDS-bound 3.3x); SPLIT=8 j-split keeps
// 2 waves/SIMD; CPAD=257 stride makes the 8 split-lanes bank-conflict-free.

#define BATCH 32
#define LA 2048
#define LB 2048
#define SPLIT 8                      // threads cooperating on one i-group (j-split)
#define MI 4                         // i-values per thread
#define CHUNK (LB / SPLIT)           // 256 j per split-thread
#define CPAD (CHUNK + 1)             // 257: pad so split-lanes hit distinct banks
#define THREADS 256
#define I_PER_BLOCK (THREADS / SPLIT * MI)   // 128
#define BLOCKS_PER_B (LA / I_PER_BLOCK)      // 16

__global__ __launch_bounds__(THREADS, 2)
void cross_attn_kernel(const float* __restrict__ a,
                       const float* __restrict__ b,
                       const float* __restrict__ w_in,
                       const float* __restrict__ b_in,
                       const float* __restrict__ w_out,
                       const float* __restrict__ b_out,
                       float* __restrict__ out)
{
    __shared__ float k_lds[SPLIT * CPAD];
    __shared__ float v_lds[SPLIT * CPAD];
    __shared__ float red[8];                 // [0..3]=per-wave kmax, [4..7]=kmin

    const int tid = threadIdx.x;
    const int bb  = blockIdx.x / BLOCKS_PER_B;
    const int cc  = blockIdx.x % BLOCKS_PER_B;

    // scalar params (uniform address -> scalar loads, L2-hit)
    const float wq = w_in[0], wk = w_in[1], wv = w_in[2];
    const float bq = b_in[0], bk = b_in[1], bv = b_in[2];
    const float ow = w_out[0], ob = b_out[0];

    // ---- stage k, v into padded LDS; track per-thread k min/max ----
    const float* brow = b + (size_t)bb * LB;
    float kmaxl = -INFINITY, kminl = INFINITY;
    {
        const int j0 = tid * 8;              // 8 consecutive j per thread, all in one chunk
        float4 b0 = *(const float4*)(brow + j0);
        float4 b1 = *(const float4*)(brow + j0 + 4);
        float bvals[8] = {b0.x, b0.y, b0.z, b0.w, b1.x, b1.y, b1.z, b1.w};
        const int base = (j0 >> 8) * CPAD + (j0 & (CHUNK - 1));
        #pragma unroll
        for (int e = 0; e < 8; ++e) {
            float kj = fmaf(bvals[e], wk, bk);
            float vj = fmaf(bvals[e], wv, bv);
            k_lds[base + e] = kj;
            v_lds[base + e] = vj;
            kmaxl = fmaxf(kmaxl, kj);
            kminl = fminf(kminl, kj);
        }
    }

    // wave-level butterfly reduce of k min/max
    #pragma unroll
    for (int off = 1; off < 64; off <<= 1) {
        kmaxl = fmaxf(kmaxl, __shfl_xor(kmaxl, off, 64));
        kminl = fminf(kminl, __shfl_xor(kminl, off, 64));
    }
    const int lane = tid & 63, wave = tid >> 6;
    if (lane == 0) { red[wave] = kmaxl; red[4 + wave] = kminl; }
    __syncthreads();
    const float kmax = fmaxf(fmaxf(red[0], red[1]), fmaxf(red[2], red[3]));
    const float kmin = fminf(fminf(red[4], red[5]), fminf(red[6], red[7]));

    // ---- per-thread setup: MI i-values, SPLIT-way j split ----
    const int split = tid & (SPLIT - 1);
    const int oct   = tid >> 3;                       // 0..31
    const int i0    = cc * I_PER_BLOCK + oct * MI;    // multiple of 4
    const float4 av = *(const float4*)(a + (size_t)bb * LA + i0);
    const float avals[MI] = {av.x, av.y, av.z, av.w};

    const float L2E = 1.4426950408889634f;
    float t2[MI], m2[MI], num[MI], den[MI];
    #pragma unroll
    for (int m = 0; m < MI; ++m) {
        float t = fmaf(avals[m], wq, bq);
        t2[m] = t * L2E;                              // exp2 domain
        m2[m] = (t2[m] >= 0.0f) ? t2[m] * kmax : t2[m] * kmin;  // = max_j t2*k_j
        num[m] = 0.0f;
        den[m] = 0.0f;
    }

    const float* kp = k_lds + split * CPAD;
    const float* vp = v_lds + split * CPAD;

    #pragma unroll 4
    for (int jj = 0; jj < CHUNK; ++jj) {
        const float kk = kp[jj];
        const float vv = vp[jj];
        #pragma unroll
        for (int m = 0; m < MI; ++m) {
            float e = __builtin_amdgcn_exp2f(fmaf(t2[m], kk, -m2[m]));
            num[m] = fmaf(e, vv, num[m]);
            den[m] += e;
        }
    }

    // butterfly reduce across the 8 split-lanes (masks 1,2,4 stay in-octet)
    #pragma unroll
    for (int mask = 1; mask < SPLIT; mask <<= 1) {
        #pragma unroll
        for (int m = 0; m < MI; ++m) {
            num[m] += __shfl_xor(num[m], mask, 64);
            den[m] += __shfl_xor(den[m], mask, 64);
        }
    }

    if (split == 0) {
        float4 res;
        float* rp = &res.x;
        #pragma unroll
        for (int m = 0; m < MI; ++m) {
            float ctx = num[m] / den[m];
            float x   = fmaf(ctx, ow, ob);
            float y   = x + avals[m];
            rp[m] = 0.5f * y * (1.0f + erff(y * 0.70710678118654752f));
        }
        *(float4*)(out + (size_t)bb * LA + i0) = res;
    }
}

extern "C" void kernel_launch(void* const* d_in, const int* in_sizes, int n_in,
                              void* d_out, int out_size, void* d_ws, size_t ws_size,
                              hipStream_t stream) {
    const float* a  = (const float*)d_in[0];
    const float* b  = (const float*)d_in[1];
    const float* wi = (const float*)d_in[2];
    const float* bi = (const float*)d_in[3];
    const float* wo = (const float*)d_in[4];
    const float* bo = (const float*)d_in[5];
    float* out = (float*)d_out;

    dim3 grid(BATCH * BLOCKS_PER_B);   // 512 blocks, 2/CU, 8 waves/CU
    dim3 block(THREADS);
    cross_attn_kernel<<<grid, block, 0, stream>>>(a, b, wi, bi, wo, bo, out);
}

// Round 2
// 83.962 us; speedup vs baseline: 1.0129x; 1.0129x over previous
//
#include <hip/hip_runtime.h>
#include <math.h>

// Problem: B=32, La=Lb=2048. embed_dim=1 MHA degenerates to:
//   q=a*wq+bq; k=b*wk+bk; v=b*wv+bv  (scalar affine)
//   ctx[b,i] = sum_j softmax_j(q_i*k_j) * v_j
//   out = gelu_exact(ctx*ow + ob + a)
// Compute-bound: 134M (i,j) pairs, 1 exp + 2 fma + 1 add each.
// Floor ~12us (trans-pipe + VALU). R1 kernel ~35-40us at 2 waves/SIMD was
// latency-stall-bound. R2: 4 waves/SIMD (SPLIT=16 -> 1024 blocks), kv packed
// float4 in LDS (1 ds_read_b128 per 2 j's), unroll-8 for load/compute overlap.

#define BATCH 32
#define LA 2048
#define LB 2048
#define SPLIT 16                     // threads cooperating on one i-group (j-split)
#define MI 4                         // i-values per thread
#define CHUNK (LB / SPLIT)           // 128 j per split-thread
#define P2 (CHUNK / 2)               // 64 float4 (kv-pair-of-2) per chunk
#define CP (P2 + 1)                  // 65: pad -> split-lanes at 2-way bank alias (free)
#define THREADS 256
#define IPB ((THREADS / SPLIT) * MI) // 64 i per block
#define BLOCKS_PER_B (LA / IPB)      // 32
// grid = 32*32 = 1024 blocks = 4096 waves = 4 waves/SIMD

__global__ __launch_bounds__(THREADS, 4)
void cross_attn_kernel(const float* __restrict__ a,
                       const float* __restrict__ b,
                       const float* __restrict__ w_in,
                       const float* __restrict__ b_in,
                       const float* __restrict__ w_out,
                       const float* __restrict__ b_out,
                       float* __restrict__ out)
{
    __shared__ float4 kv[SPLIT * CP];        // {k(2p), v(2p), k(2p+1), v(2p+1)}
    __shared__ float red[8];                 // [0..3]=per-wave kmax, [4..7]=kmin

    const int tid = threadIdx.x;
    const int bb  = blockIdx.x / BLOCKS_PER_B;
    const int cc  = blockIdx.x % BLOCKS_PER_B;

    // scalar params (uniform -> s_load, L2-hit)
    const float wq = w_in[0], wk = w_in[1], wv = w_in[2];
    const float bq = b_in[0], bk = b_in[1], bv = b_in[2];
    const float ow = w_out[0], ob = b_out[0];

    // ---- stage k,v into packed+padded LDS; track per-thread k min/max ----
    const float* brow = b + (size_t)bb * LB;
    float kmaxl = -INFINITY, kminl = INFINITY;
    {
        const int j0 = tid * 8;              // 8 consecutive j, all within one chunk
        float4 b0 = *(const float4*)(brow + j0);
        float4 b1 = *(const float4*)(brow + j0 + 4);
        float bv8[8] = {b0.x, b0.y, b0.z, b0.w, b1.x, b1.y, b1.z, b1.w};
        const int c  = j0 >> 7;                        // chunk index (0..15)
        const int pi = (j0 & (CHUNK - 1)) >> 1;        // float4 index in chunk
        float4* dst = &kv[c * CP + pi];
        #pragma unroll
        for (int e = 0; e < 4; ++e) {
            float k0 = fmaf(bv8[2 * e],     wk, bk);
            float v0 = fmaf(bv8[2 * e],     wv, bv);
            float k1 = fmaf(bv8[2 * e + 1], wk, bk);
            float v1 = fmaf(bv8[2 * e + 1], wv, bv);
            dst[e] = make_float4(k0, v0, k1, v1);
            kmaxl = fmaxf(kmaxl, fmaxf(k0, k1));
            kminl = fminf(kminl, fminf(k0, k1));
        }
    }

    // wave butterfly reduce of k min/max, then cross-wave via LDS
    #pragma unroll
    for (int off = 1; off < 64; off <<= 1) {
        kmaxl = fmaxf(kmaxl, __shfl_xor(kmaxl, off, 64));
        kminl = fminf(kminl, __shfl_xor(kminl, off, 64));
    }
    const int lane = tid & 63, wave = tid >> 6;
    if (lane == 0) { red[wave] = kmaxl; red[4 + wave] = kminl; }
    __syncthreads();
    const float kmax = fmaxf(fmaxf(red[0], red[1]), fmaxf(red[2], red[3]));
    const float kmin = fminf(fminf(red[4], red[5]), fminf(red[6], red[7]));

    // ---- per-thread setup: MI i-values, SPLIT-way j split ----
    const int split = tid & (SPLIT - 1);
    const int g     = tid >> 4;                       // 0..15 i-groups per block
    const int i0    = cc * IPB + g * MI;              // multiple of 4
    const float4 av = *(const float4*)(a + (size_t)bb * LA + i0);
    const float avals[MI] = {av.x, av.y, av.z, av.w};

    const float L2E = 1.4426950408889634f;
    float t2[MI], nm2[MI], num[MI], den[MI];
    #pragma unroll
    for (int m = 0; m < MI; ++m) {
        float t = fmaf(avals[m], wq, bq);
        t2[m]  = t * L2E;                                        // exp2 domain
        nm2[m] = -((t2[m] >= 0.0f) ? t2[m] * kmax : t2[m] * kmin); // -max_j t2*k_j
        num[m] = 0.0f;
        den[m] = 0.0f;
    }

    const float4* kvp = &kv[split * CP];

    #pragma unroll 8
    for (int p = 0; p < P2; ++p) {
        const float4 q = kvp[p];                      // k0,v0,k1,v1
        #pragma unroll
        for (int m = 0; m < MI; ++m) {
            float e0 = __builtin_amdgcn_exp2f(fmaf(t2[m], q.x, nm2[m]));
            num[m] = fmaf(e0, q.y, num[m]);
            den[m] += e0;
            float e1 = __builtin_amdgcn_exp2f(fmaf(t2[m], q.z, nm2[m]));
            num[m] = fmaf(e1, q.w, num[m]);
            den[m] += e1;
        }
    }

    // butterfly reduce across the 16 split-lanes (masks 1,2,4,8 stay in-group)
    #pragma unroll
    for (int mask = 1; mask < SPLIT; mask <<= 1) {
        #pragma unroll
        for (int m = 0; m < MI; ++m) {
            num[m] += __shfl_xor(num[m], mask, 64);
            den[m] += __shfl_xor(den[m], mask, 64);
        }
    }

    if (split == 0) {
        float4 res;
        float* rp = &res.x;
        #pragma unroll
        for (int m = 0; m < MI; ++m) {
            float ctx = num[m] / den[m];
            float x   = fmaf(ctx, ow, ob);
            float y   = x + avals[m];
            rp[m] = 0.5f * y * (1.0f + erff(y * 0.70710678118654752f));
        }
        *(float4*)(out + (size_t)bb * LA + i0) = res;
    }
}

extern "C" void kernel_launch(void* const* d_in, const int* in_sizes, int n_in,
                              void* d_out, int out_size, void* d_ws, size_t ws_size,
                              hipStream_t stream) {
    const float* a  = (const float*)d_in[0];
    const float* b  = (const float*)d_in[1];
    const float* wi = (const float*)d_in[2];
    const float* bi = (const float*)d_in[3];
    const float* wo = (const float*)d_in[4];
    const float* bo = (const float*)d_in[5];
    float* out = (float*)d_out;

    dim3 grid(BATCH * BLOCKS_PER_B);   // 1024 blocks -> 4 waves/SIMD
    dim3 block(THREADS);
    cross_attn_kernel<<<grid, block, 0, stream>>>(a, b, wi, bi, wo, bo, out);
}